// Round 3
// baseline (29.756 us; speedup 1.0000x reference)
//
#include <hip/hip_runtime.h>
#include <math.h>

#define N 8192
#define NP 4096
#define NBLK 256
#define DONE_MAGIC 0x5EED5EEDu

// Monotone total-order key: K_k > K_j  <=>  t_k > t_j || (t_k == t_j && k < j)
// (stable descending argsort rank predicate).
__device__ __forceinline__ unsigned int fkey(float x) {
    unsigned int u = __float_as_uint(x);
    unsigned int m = (unsigned int)((int)u >> 31) | 0x80000000u;
    return u ^ m;
}
__device__ __forceinline__ unsigned long long fullkey(float x, int k) {
    return ((unsigned long long)fkey(x) << 13) | (unsigned long long)(N - 1 - k);
}

// Fused: phase 1 (all 256 blocks) rank via ballot+popcount, scatter e^p / e^-p
// to sorted position, per-block partial sum of +-p. Last-block pattern:
// threadfence + release flag; block 0 spins (acquire), then phase 2 computes
// the closed-form loss:
//   E_i = sum_{m in [i, N-i)} e^{f_m},  G_i = same for e^{-f_m}
//   denom_i = E_i*G_i - (N - 2i)
//   loss = -( sum_i (f_i - f_{N-1-i}) - sum_i log(denom_i) ) = L - F
__global__ void __launch_bounds__(256) fused_kernel(
    const float* __restrict__ pred,
    const float* __restrict__ target,
    float* __restrict__ ws,
    float* __restrict__ out)
{
    float* ea = ws;                                    // [0, 8192) e^{f_m}
    float* eb = ws + N;                                // [8192, 16384) e^{-f_m}
    double* part = (double*)(ws + 2 * N);              // 256 doubles (byte 65536)
    unsigned int* flags = (unsigned int*)(ws + 2 * N + 512);  // 256 uints

    const int t    = threadIdx.x;
    const int lane = t & 63;
    const int wv   = t >> 6;
    const int b    = blockIdx.x;

    __shared__ float sWS[4];
    __shared__ float sWA[4], sWB[4];
    __shared__ double sL[4];

    // ---------------- Phase 1: rank + scatter ----------------
    const int jbase = (b * 4 + wv) * 8;

    unsigned long long Kj[8];
    #pragma unroll
    for (int jj = 0; jj < 8; ++jj)
        Kj[jj] = fullkey(target[jbase + jj], jbase + jj);

    int cnt[8] = {0,0,0,0,0,0,0,0};

    #pragma unroll 2
    for (int it = 0; it < N / 256; ++it) {
        const int kb = it * 256 + lane * 4;
        const float4 tv = *reinterpret_cast<const float4*>(target + kb);
        unsigned long long Kk[4];
        Kk[0] = fullkey(tv.x, kb);
        Kk[1] = fullkey(tv.y, kb + 1);
        Kk[2] = fullkey(tv.z, kb + 2);
        Kk[3] = fullkey(tv.w, kb + 3);
        #pragma unroll
        for (int jj = 0; jj < 8; ++jj) {
            cnt[jj] += __popcll(__ballot(Kk[0] > Kj[jj]));
            cnt[jj] += __popcll(__ballot(Kk[1] > Kj[jj]));
            cnt[jj] += __popcll(__ballot(Kk[2] > Kj[jj]));
            cnt[jj] += __popcll(__ballot(Kk[3] > Kj[jj]));
        }
    }

    // lane jj scatters element jbase+jj; cnt[] is wave-uniform (ballot-based)
    float sv = 0.f;
    #pragma unroll
    for (int jj = 0; jj < 8; ++jj) {
        if (lane == jj) {
            const float p = pred[jbase + jj];
            const float e = __expf(p);
            ea[cnt[jj]] = e;
            eb[cnt[jj]] = __builtin_amdgcn_rcpf(e);
            sv = (cnt[jj] < NP) ? p : -p;   // contribution to F
        }
    }
    // fold lanes 0..7 (others carry 0)
    sv += __shfl_xor(sv, 1, 64);
    sv += __shfl_xor(sv, 2, 64);
    sv += __shfl_xor(sv, 4, 64);
    if (lane == 0) sWS[wv] = sv;
    __syncthreads();   // all waves' global stores drained (vmcnt) + LDS visible

    if (t == 0) {
        part[b] = (double)(sWS[0] + sWS[1] + sWS[2] + sWS[3]);
        __threadfence();   // agent-scope release: flush this XCD's L2
        if (b != 0)
            __hip_atomic_store(&flags[b], DONE_MAGIC,
                               __ATOMIC_RELEASE, __HIP_MEMORY_SCOPE_AGENT);
    }
    if (b != 0) return;

    // ---------------- Block 0: wait for all 255 producers ----------------
    if (t >= 1) {
        while (__hip_atomic_load(&flags[t], __ATOMIC_ACQUIRE,
                                 __HIP_MEMORY_SCOPE_AGENT) != DONE_MAGIC)
            __builtin_amdgcn_s_sleep(2);
        // reset for next graph replay
        __hip_atomic_store(&flags[t], 0u, __ATOMIC_RELAXED,
                           __HIP_MEMORY_SCOPE_AGENT);
    }
    __syncthreads();
    __threadfence();   // acquire side: invalidate caches before reading ea/eb/part

    // ---------------- Phase 2: loss (256 threads, 16 i's each) ----------------
    const int base = t * 16;
    const float4* eaf = (const float4*)(ea + base);
    const float4* ebf = (const float4*)(eb + base);
    const float4* ear = (const float4*)(ea + (N - 16 - base));
    const float4* ebr = (const float4*)(eb + (N - 16 - base));

    float a[16], bv[16];
    float sa = 0.f, sb = 0.f;
    #pragma unroll
    for (int q = 0; q < 4; ++q) {
        const float4 va4 = eaf[q];
        const float4 wa4 = ear[3 - q];
        a[4*q+0] = va4.x + wa4.w;  a[4*q+1] = va4.y + wa4.z;
        a[4*q+2] = va4.z + wa4.y;  a[4*q+3] = va4.w + wa4.x;
        const float4 vb4 = ebf[q];
        const float4 wb4 = ebr[3 - q];
        bv[4*q+0] = vb4.x + wb4.w; bv[4*q+1] = vb4.y + wb4.z;
        bv[4*q+2] = vb4.z + wb4.y; bv[4*q+3] = vb4.w + wb4.x;
    }
    #pragma unroll
    for (int c = 0; c < 16; ++c) { sa += a[c]; sb += bv[c]; }

    // wave-64 inclusive shuffle scan of per-thread sums
    float va = sa, vb = sb;
    #pragma unroll
    for (int off = 1; off < 64; off <<= 1) {
        const float ua = __shfl_up(va, off, 64);
        const float ub = __shfl_up(vb, off, 64);
        if (lane >= off) { va += ua; vb += ub; }
    }
    if (lane == 63) { sWA[wv] = va; sWB[wv] = vb; }
    __syncthreads();

    float TA = 0.f, TB = 0.f, wpA = 0.f, wpB = 0.f;
    #pragma unroll
    for (int w2 = 0; w2 < 4; ++w2) {
        const float xa = sWA[w2];
        const float xb = sWB[w2];
        TA += xa; TB += xb;
        if (w2 < wv) { wpA += xa; wpB += xb; }
    }
    const float exA = wpA + (va - sa);
    const float exB = wpB + (vb - sb);

    float runA = 0.f, runB = 0.f;
    float logsum = 0.f;
    #pragma unroll
    for (int c = 0; c < 16; ++c) {
        const int i = base + c;
        const float E = TA - exA - runA;
        const float G = TB - exB - runB;
        runA += a[c];
        runB += bv[c];
        float denom = E * G - (float)(N - 2 * i);
        if (denom <= 0.f) denom = 1e-8f;
        logsum += __logf(denom);
    }

    // out = L - F: per-thread partial = sum(log) - part[t]
    double lsum = (double)logsum - part[t];
    #pragma unroll
    for (int off = 32; off > 0; off >>= 1)
        lsum += __shfl_xor(lsum, off, 64);
    if (lane == 0) sL[wv] = lsum;
    __syncthreads();
    if (t == 0)
        out[0] = (float)(sL[0] + sL[1] + sL[2] + sL[3]);
}

extern "C" void kernel_launch(void* const* d_in, const int* in_sizes, int n_in,
                              void* d_out, int out_size, void* d_ws, size_t ws_size,
                              hipStream_t stream)
{
    const float* pred   = (const float*)d_in[0];
    const float* target = (const float*)d_in[1];
    float* out = (float*)d_out;
    float* ws  = (float*)d_ws;

    fused_kernel<<<NBLK, 256, 0, stream>>>(pred, target, ws, out);
}